// Round 1
// baseline (580.950 us; speedup 1.0000x reference)
//
#include <hip/hip_runtime.h>
#include <math.h>

// ---------------------------------------------------------------------------
// GNNEncoder: 3x GCNConv(relu) -> sum of layers -> global_mean_pool -> MLP
// Strategy: build CSR (incoming edges per dst) once per launch, then each conv
// is gather-based (no float atomics). Pool uses sorted batch + binary search.
// ---------------------------------------------------------------------------

__global__ void k_zero(int* __restrict__ p, int n) {
    int i = blockIdx.x * blockDim.x + threadIdx.x;
    if (i < n) p[i] = 0;
}

__global__ void k_hist(const int* __restrict__ dst, int* __restrict__ count, int E) {
    int e = blockIdx.x * blockDim.x + threadIdx.x;
    if (e < E) atomicAdd(&count[dst[e]], 1);
}

__global__ void k_dis(const int* __restrict__ count, float* __restrict__ dis, int n) {
    int i = blockIdx.x * blockDim.x + threadIdx.x;
    if (i < n) dis[i] = rsqrtf((float)(count[i] + 1));  // +1 self-loop
}

// per-block sums of count (256 elems/block)
__global__ void k_scan1(const int* __restrict__ count, int* __restrict__ bsum, int n) {
    __shared__ int s[256];
    int t = threadIdx.x;
    int i = blockIdx.x * 256 + t;
    s[t] = (i < n) ? count[i] : 0;
    __syncthreads();
    for (int st = 128; st > 0; st >>= 1) {
        if (t < st) s[t] += s[t + st];
        __syncthreads();
    }
    if (t == 0) bsum[blockIdx.x] = s[0];
}

// single-block exclusive scan of block sums (nb <= 256)
__global__ void k_scan2(int* __restrict__ bsum, int nb) {
    __shared__ int s[256];
    int t = threadIdx.x;
    s[t] = (t < nb) ? bsum[t] : 0;
    __syncthreads();
    for (int st = 1; st < 256; st <<= 1) {
        int v = s[t];
        if (t >= st) v += s[t - st];
        __syncthreads();
        s[t] = v;
        __syncthreads();
    }
    if (t < nb) bsum[t] = (t == 0) ? 0 : s[t - 1];
}

// per-block exclusive scan + add block offset -> offs, cursor
__global__ void k_scan3(const int* __restrict__ count, const int* __restrict__ boffs,
                        int* __restrict__ offs, int* __restrict__ cursor, int n) {
    __shared__ int s[256];
    int t = threadIdx.x;
    int i = blockIdx.x * 256 + t;
    int c = (i < n) ? count[i] : 0;
    s[t] = c;
    __syncthreads();
    for (int st = 1; st < 256; st <<= 1) {
        int v = s[t];
        if (t >= st) v += s[t - st];
        __syncthreads();
        s[t] = v;
        __syncthreads();
    }
    int excl = s[t] - c;
    int off = boffs[blockIdx.x] + excl;
    if (i < n) {
        offs[i] = off;
        cursor[i] = off;
        if (i == n - 1) offs[n] = off + c;
    }
}

__global__ void k_fill(const int* __restrict__ src, const int* __restrict__ dst,
                       int* __restrict__ cursor, int* __restrict__ col, int E) {
    int e = blockIdx.x * blockDim.x + threadIdx.x;
    if (e < E) {
        int d = dst[e];
        int p = atomicAdd(&cursor[d], 1);
        col[p] = src[e];
    }
}

// H[n][j] = sum_k X[n][k] * W[k][j]   (4 nodes per 256-thread block, W in LDS)
template <int K>
__global__ void k_gemm(const float* __restrict__ X, const float* __restrict__ W,
                       float* __restrict__ H, int n) {
    __shared__ float w[K * 64];
    int t = threadIdx.x;
    for (int idx = t; idx < K * 64; idx += 256) w[idx] = W[idx];
    __syncthreads();
    int node = blockIdx.x * 4 + (t >> 6);
    if (node >= n) return;
    int j = t & 63;
    const float* xr = X + (size_t)node * K;
    float acc = 0.f;
#pragma unroll 16
    for (int k = 0; k < K; k++) acc += xr[k] * w[k * 64 + j];
    H[(size_t)node * 64 + j] = acc;
}

// Xout[n][j] = relu( dn * (H[n][j]*dn_self + sum_{s in in(n)} H[s][j]*dis[s]) + b[j] )
// self-loop norm = dis[n]^2; edge norm = dis[s]*dis[n]
__global__ void k_agg(const float* __restrict__ H, const int* __restrict__ col,
                      const int* __restrict__ offs, const float* __restrict__ dis,
                      const float* __restrict__ bias, float* __restrict__ Xout,
                      float* __restrict__ S, int mode, int n) {
    int t = threadIdx.x;
    int node = blockIdx.x * 4 + (t >> 6);
    if (node >= n) return;
    int j = t & 63;
    float dn = dis[node];
    float acc = H[(size_t)node * 64 + j] * dn;  // self contribution (pre-final *dn)
    int lo = offs[node], hi = offs[node + 1];
    for (int p = lo; p < hi; p++) {
        int s = col[p];
        acc += H[(size_t)s * 64 + j] * dis[s];
    }
    float v = acc * dn + bias[j];
    v = v > 0.f ? v : 0.f;
    Xout[(size_t)node * 64 + j] = v;
    if (mode == 0)
        S[(size_t)node * 64 + j] = v;
    else
        S[(size_t)node * 64 + j] += v;
}

// one wave per graph: segment-mean via binary search on sorted batch, then MLP head
__global__ void k_poolhead(const float* __restrict__ S, const int* __restrict__ batch,
                           const float* __restrict__ Wp1, const float* __restrict__ bp1,
                           const float* __restrict__ Wp2, const float* __restrict__ bp2,
                           float* __restrict__ out, int n, int G) {
    int g = blockIdx.x;
    int j = threadIdx.x;  // 0..63
    // lower_bound(batch, g) and lower_bound(batch, g+1)
    int a = 0, b = n;
    while (a < b) { int m = (a + b) >> 1; if (batch[m] < g) a = m + 1; else b = m; }
    int beg = a;
    b = n;
    while (a < b) { int m = (a + b) >> 1; if (batch[m] < g + 1) a = m + 1; else b = m; }
    int end = a;
    float sum = 0.f;
    for (int i = beg; i < end; i++) sum += S[(size_t)i * 64 + j];
    float cnt = (float)(end - beg);
    float p = sum / fmaxf(cnt, 1.f);
    __shared__ float ps[64];
    __shared__ float ts[64];
    ps[j] = p;
    __syncthreads();
    float t1 = bp1[j];
#pragma unroll 8
    for (int k = 0; k < 64; k++) t1 += ps[k] * Wp1[k * 64 + j];
    t1 = fmaxf(t1, 0.f);
    ts[j] = t1;
    __syncthreads();
    if (j < 32) {
        float o = bp2[j];
#pragma unroll 8
        for (int k = 0; k < 64; k++) o += ts[k] * Wp2[k * 32 + j];
        out[(size_t)g * 32 + j] = o;
    }
}

extern "C" void kernel_launch(void* const* d_in, const int* in_sizes, int n_in,
                              void* d_out, int out_size, void* d_ws, size_t ws_size,
                              hipStream_t stream) {
    const float* x   = (const float*)d_in[0];
    const int*   ei  = (const int*)d_in[1];
    const int*   bat = (const int*)d_in[2];
    const float* W1  = (const float*)d_in[3];
    const float* b1  = (const float*)d_in[4];
    const float* W2  = (const float*)d_in[5];
    const float* b2  = (const float*)d_in[6];
    const float* W3  = (const float*)d_in[7];
    const float* b3  = (const float*)d_in[8];
    const float* Wp1 = (const float*)d_in[9];
    const float* bp1 = (const float*)d_in[10];
    const float* Wp2 = (const float*)d_in[11];
    const float* bp2 = (const float*)d_in[12];

    int N = in_sizes[0] / 128;
    int E = in_sizes[1] / 2;
    int G = out_size / 32;
    const int* src = ei;
    const int* dst = ei + E;

    // workspace carve (all fully initialized before use; 0xAA poison is fine)
    char* w = (char*)d_ws;
    auto alloc = [&](size_t bytes) -> void* {
        void* p = (void*)w;
        w += (bytes + 255) & ~(size_t)255;
        return p;
    };
    int NB = (N + 255) / 256;  // 196 for N=50000; must be <=256 for k_scan2
    int*   count  = (int*)alloc((size_t)N * 4);
    int*   offs   = (int*)alloc((size_t)(N + 1) * 4);
    int*   cursor = (int*)alloc((size_t)N * 4);
    int*   col    = (int*)alloc((size_t)E * 4);
    int*   bsum   = (int*)alloc((size_t)NB * 4);
    float* dis    = (float*)alloc((size_t)N * 4);
    float* A      = (float*)alloc((size_t)N * 64 * 4);
    float* B      = (float*)alloc((size_t)N * 64 * 4);
    float* S      = (float*)alloc((size_t)N * 64 * 4);

    int EB = (E + 255) / 256;
    k_zero<<<NB, 256, 0, stream>>>(count, N);
    k_hist<<<EB, 256, 0, stream>>>(dst, count, E);
    k_dis<<<NB, 256, 0, stream>>>(count, dis, N);
    k_scan1<<<NB, 256, 0, stream>>>(count, bsum, N);
    k_scan2<<<1, 256, 0, stream>>>(bsum, NB);
    k_scan3<<<NB, 256, 0, stream>>>(count, bsum, offs, cursor, N);
    k_fill<<<EB, 256, 0, stream>>>(src, dst, cursor, col, E);

    int NB4 = (N + 3) / 4;
    k_gemm<128><<<NB4, 256, 0, stream>>>(x, W1, B, N);
    k_agg<<<NB4, 256, 0, stream>>>(B, col, offs, dis, b1, A, S, 0, N);
    k_gemm<64><<<NB4, 256, 0, stream>>>(A, W2, B, N);
    k_agg<<<NB4, 256, 0, stream>>>(B, col, offs, dis, b2, A, S, 1, N);
    k_gemm<64><<<NB4, 256, 0, stream>>>(A, W3, B, N);
    k_agg<<<NB4, 256, 0, stream>>>(B, col, offs, dis, b3, A, S, 1, N);

    k_poolhead<<<G, 64, 0, stream>>>(S, bat, Wp1, bp1, Wp2, bp2, (float*)d_out, N, G);
}

// Round 2
// 342.796 us; speedup vs baseline: 1.6947x; 1.6947x over previous
//
#include <hip/hip_runtime.h>
#include <math.h>

// ---------------------------------------------------------------------------
// GNNEncoder: 3x GCNConv(relu) -> sum of layers -> global_mean_pool -> MLP
// CSR (incoming edges per dst) built per launch; convs are gather-based.
// Layout: 16 lanes per node x float4 channels (64 ch) -> 4 nodes/wave,
// 4 independent gather chains per wave + 2x edge unroll for MLP.
// ---------------------------------------------------------------------------

__device__ inline float4 f4fma(float s, float4 a, float4 acc) {
    acc.x += s * a.x; acc.y += s * a.y; acc.z += s * a.z; acc.w += s * a.w;
    return acc;
}

__global__ void k_zero(int* __restrict__ p, int n) {
    int i = blockIdx.x * blockDim.x + threadIdx.x;
    if (i < n) p[i] = 0;
}

__global__ void k_hist(const int* __restrict__ dst, int* __restrict__ count, int E) {
    int e = blockIdx.x * blockDim.x + threadIdx.x;
    if (e < E) atomicAdd(&count[dst[e]], 1);
}

__global__ void k_dis(const int* __restrict__ count, float* __restrict__ dis, int n) {
    int i = blockIdx.x * blockDim.x + threadIdx.x;
    if (i < n) dis[i] = rsqrtf((float)(count[i] + 1));  // +1 self-loop
}

__global__ void k_scan1(const int* __restrict__ count, int* __restrict__ bsum, int n) {
    __shared__ int s[256];
    int t = threadIdx.x;
    int i = blockIdx.x * 256 + t;
    s[t] = (i < n) ? count[i] : 0;
    __syncthreads();
    for (int st = 128; st > 0; st >>= 1) {
        if (t < st) s[t] += s[t + st];
        __syncthreads();
    }
    if (t == 0) bsum[blockIdx.x] = s[0];
}

__global__ void k_scan2(int* __restrict__ bsum, int nb) {
    __shared__ int s[256];
    int t = threadIdx.x;
    s[t] = (t < nb) ? bsum[t] : 0;
    __syncthreads();
    for (int st = 1; st < 256; st <<= 1) {
        int v = s[t];
        if (t >= st) v += s[t - st];
        __syncthreads();
        s[t] = v;
        __syncthreads();
    }
    if (t < nb) bsum[t] = (t == 0) ? 0 : s[t - 1];
}

__global__ void k_scan3(const int* __restrict__ count, const int* __restrict__ boffs,
                        int* __restrict__ offs, int* __restrict__ cursor, int n) {
    __shared__ int s[256];
    int t = threadIdx.x;
    int i = blockIdx.x * 256 + t;
    int c = (i < n) ? count[i] : 0;
    s[t] = c;
    __syncthreads();
    for (int st = 1; st < 256; st <<= 1) {
        int v = s[t];
        if (t >= st) v += s[t - st];
        __syncthreads();
        s[t] = v;
        __syncthreads();
    }
    int excl = s[t] - c;
    int off = boffs[blockIdx.x] + excl;
    if (i < n) {
        offs[i] = off;
        cursor[i] = off;
        if (i == n - 1) offs[n] = off + c;
    }
}

__global__ void k_fill(const int* __restrict__ src, const int* __restrict__ dst,
                       int* __restrict__ cursor, int* __restrict__ col, int E) {
    int e = blockIdx.x * blockDim.x + threadIdx.x;
    if (e < E) {
        int d = dst[e];
        int p = atomicAdd(&cursor[d], 1);
        col[p] = src[e];
    }
}

// H[n][0:64] = X[n][0:K] @ W[K][64]. 16 nodes/block, 16 lanes x float4 per node.
template <int K>
__global__ void k_gemm(const float* __restrict__ X, const float* __restrict__ W,
                       float* __restrict__ H, int n) {
    __shared__ float4 w4[K * 16];
    int t = threadIdx.x;
    const float4* W4 = (const float4*)W;
    for (int i = t; i < K * 16; i += 256) w4[i] = W4[i];
    __syncthreads();
    int node = blockIdx.x * 16 + (t >> 4);
    if (node >= n) return;
    int j4 = t & 15;
    const float4* X4 = (const float4*)(X + (size_t)node * K);
    float4 acc = make_float4(0.f, 0.f, 0.f, 0.f);
#pragma unroll 4
    for (int k0 = 0; k0 < K; k0 += 4) {
        float4 xv = X4[k0 >> 2];  // uniform across the 16-lane node group
        float4 a = w4[(k0 + 0) * 16 + j4];
        float4 b = w4[(k0 + 1) * 16 + j4];
        float4 c = w4[(k0 + 2) * 16 + j4];
        float4 d = w4[(k0 + 3) * 16 + j4];
        acc = f4fma(xv.x, a, acc);
        acc = f4fma(xv.y, b, acc);
        acc = f4fma(xv.z, c, acc);
        acc = f4fma(xv.w, d, acc);
    }
    ((float4*)H)[(size_t)node * 16 + j4] = acc;
}

// Out[n] = relu( dn*(H[n]*dn + sum_{s in in(n)} H[s]*dis[s]) + b ) [+ add1[n]+add2[n]]
__global__ void k_agg(const float* __restrict__ H, const int* __restrict__ col,
                      const int* __restrict__ offs, const float* __restrict__ dis,
                      const float* __restrict__ bias, const float* __restrict__ add1,
                      const float* __restrict__ add2, float* __restrict__ Out, int n) {
    int t = threadIdx.x;
    int node = blockIdx.x * 16 + (t >> 4);
    if (node >= n) return;
    int j4 = t & 15;
    const float4* H4 = (const float4*)H;
    float dn = dis[node];
    float4 acc = H4[(size_t)node * 16 + j4];
    acc.x *= dn; acc.y *= dn; acc.z *= dn; acc.w *= dn;  // self-loop (x dn again later)
    int lo = offs[node], hi = offs[node + 1];
    int p = lo;
    for (; p + 2 <= hi; p += 2) {
        int s0 = col[p], s1 = col[p + 1];
        float w0 = dis[s0], w1 = dis[s1];
        float4 h0 = H4[(size_t)s0 * 16 + j4];
        float4 h1 = H4[(size_t)s1 * 16 + j4];
        acc = f4fma(w0, h0, acc);
        acc = f4fma(w1, h1, acc);
    }
    if (p < hi) {
        int s0 = col[p];
        acc = f4fma(dis[s0], H4[(size_t)s0 * 16 + j4], acc);
    }
    float4 b = ((const float4*)bias)[j4];
    float4 v;
    v.x = fmaxf(acc.x * dn + b.x, 0.f);
    v.y = fmaxf(acc.y * dn + b.y, 0.f);
    v.z = fmaxf(acc.z * dn + b.z, 0.f);
    v.w = fmaxf(acc.w * dn + b.w, 0.f);
    if (add1) {
        float4 a1 = ((const float4*)add1)[(size_t)node * 16 + j4];
        float4 a2 = ((const float4*)add2)[(size_t)node * 16 + j4];
        v.x += a1.x + a2.x; v.y += a1.y + a2.y; v.z += a1.z + a2.z; v.w += a1.w + a2.w;
    }
    ((float4*)Out)[(size_t)node * 16 + j4] = v;
}

// one 64-thread block per graph: segment mean (sorted batch, binary search) + MLP head
__global__ void k_poolhead(const float* __restrict__ S, const int* __restrict__ batch,
                           const float* __restrict__ Wp1, const float* __restrict__ bp1,
                           const float* __restrict__ Wp2, const float* __restrict__ bp2,
                           float* __restrict__ out, int n, int G) {
    int g = blockIdx.x;
    int j = threadIdx.x;  // 0..63
    int a = 0, b = n;
    while (a < b) { int m = (a + b) >> 1; if (batch[m] < g) a = m + 1; else b = m; }
    int beg = a;
    b = n;
    while (a < b) { int m = (a + b) >> 1; if (batch[m] < g + 1) a = m + 1; else b = m; }
    int end = a;
    float sum = 0.f;
    int i = beg;
    for (; i + 2 <= end; i += 2)
        sum += S[(size_t)i * 64 + j] + S[(size_t)(i + 1) * 64 + j];
    if (i < end) sum += S[(size_t)i * 64 + j];
    float cnt = (float)(end - beg);
    float p = sum / fmaxf(cnt, 1.f);
    __shared__ float ps[64];
    __shared__ float ts[64];
    ps[j] = p;
    __syncthreads();
    float t1 = bp1[j];
#pragma unroll 8
    for (int k = 0; k < 64; k++) t1 += ps[k] * Wp1[k * 64 + j];
    t1 = fmaxf(t1, 0.f);
    ts[j] = t1;
    __syncthreads();
    if (j < 32) {
        float o = bp2[j];
#pragma unroll 8
        for (int k = 0; k < 64; k++) o += ts[k] * Wp2[k * 32 + j];
        out[(size_t)g * 32 + j] = o;
    }
}

extern "C" void kernel_launch(void* const* d_in, const int* in_sizes, int n_in,
                              void* d_out, int out_size, void* d_ws, size_t ws_size,
                              hipStream_t stream) {
    const float* x   = (const float*)d_in[0];
    const int*   ei  = (const int*)d_in[1];
    const int*   bat = (const int*)d_in[2];
    const float* W1  = (const float*)d_in[3];
    const float* b1  = (const float*)d_in[4];
    const float* W2  = (const float*)d_in[5];
    const float* b2  = (const float*)d_in[6];
    const float* W3  = (const float*)d_in[7];
    const float* b3  = (const float*)d_in[8];
    const float* Wp1 = (const float*)d_in[9];
    const float* bp1 = (const float*)d_in[10];
    const float* Wp2 = (const float*)d_in[11];
    const float* bp2 = (const float*)d_in[12];

    int N = in_sizes[0] / 128;
    int E = in_sizes[1] / 2;
    int G = out_size / 32;
    const int* src = ei;
    const int* dst = ei + E;

    char* w = (char*)d_ws;
    auto alloc = [&](size_t bytes) -> void* {
        void* p = (void*)w;
        w += (bytes + 255) & ~(size_t)255;
        return p;
    };
    int NB = (N + 255) / 256;  // must be <= 256 for k_scan2
    int*   count  = (int*)alloc((size_t)N * 4);
    int*   offs   = (int*)alloc((size_t)(N + 1) * 4);
    int*   cursor = (int*)alloc((size_t)N * 4);
    int*   col    = (int*)alloc((size_t)E * 4);
    int*   bsum   = (int*)alloc((size_t)NB * 4);
    float* dis    = (float*)alloc((size_t)N * 4);
    float* Hb     = (float*)alloc((size_t)N * 64 * 4);
    float* X1     = (float*)alloc((size_t)N * 64 * 4);
    float* X2     = (float*)alloc((size_t)N * 64 * 4);
    float* S      = (float*)alloc((size_t)N * 64 * 4);

    int EB = (E + 255) / 256;
    k_zero<<<NB, 256, 0, stream>>>(count, N);
    k_hist<<<EB, 256, 0, stream>>>(dst, count, E);
    k_dis<<<NB, 256, 0, stream>>>(count, dis, N);
    k_scan1<<<NB, 256, 0, stream>>>(count, bsum, N);
    k_scan2<<<1, 256, 0, stream>>>(bsum, NB);
    k_scan3<<<NB, 256, 0, stream>>>(count, bsum, offs, cursor, N);
    k_fill<<<EB, 256, 0, stream>>>(src, dst, cursor, col, E);

    int NB16 = (N + 15) / 16;
    k_gemm<128><<<NB16, 256, 0, stream>>>(x, W1, Hb, N);
    k_agg<<<NB16, 256, 0, stream>>>(Hb, col, offs, dis, b1, nullptr, nullptr, X1, N);
    k_gemm<64><<<NB16, 256, 0, stream>>>(X1, W2, Hb, N);
    k_agg<<<NB16, 256, 0, stream>>>(Hb, col, offs, dis, b2, nullptr, nullptr, X2, N);
    k_gemm<64><<<NB16, 256, 0, stream>>>(X2, W3, Hb, N);
    k_agg<<<NB16, 256, 0, stream>>>(Hb, col, offs, dis, b3, X1, X2, S, N);

    k_poolhead<<<G, 64, 0, stream>>>(S, bat, Wp1, bp1, Wp2, bp2, (float*)d_out, N, G);
}

// Round 3
// 290.925 us; speedup vs baseline: 1.9969x; 1.1783x over previous
//
#include <hip/hip_runtime.h>
#include <math.h>

// ---------------------------------------------------------------------------
// GNNEncoder: 3x GCNConv(relu) -> sum of layers -> global_mean_pool -> MLP
// CSR built per launch via two-level bucketed counting sort (no global-atomic
// scatter: every global write is block-contiguous -> write amp ~1).
// Convs are gather-based: 16 lanes/node x float4 channels.
// ---------------------------------------------------------------------------

__device__ inline float4 f4fma(float s, float4 a, float4 acc) {
    acc.x += s * a.x; acc.y += s * a.y; acc.z += s * a.z; acc.w += s * a.w;
    return acc;
}

// ---------------- pass A: coarse bucket sort of edges by dst>>8 -------------

// per-chunk LDS histogram of coarse buckets
__global__ void kA_hist(const int* __restrict__ dst, int* __restrict__ hist,
                        int E, int chunk) {
    __shared__ int h[256];
    int t = threadIdx.x;
    h[t] = 0;
    __syncthreads();
    int e0 = blockIdx.x * chunk;
    int e1 = min(e0 + chunk, E);
    for (int e = e0 + t; e < e1; e += 256) atomicAdd(&h[dst[e] >> 8], 1);
    __syncthreads();
    hist[blockIdx.x * 256 + t] = h[t];
}

// block k scans column k of hist (over 256 chunk-blocks) -> exclusive cursors
__global__ void kA_colscan(const int* __restrict__ hist, int* __restrict__ cursorA,
                           int* __restrict__ tot) {
    __shared__ int s[256];
    int t = threadIdx.x;
    int k = blockIdx.x;
    int v = hist[t * 256 + k];
    s[t] = v;
    __syncthreads();
    for (int st = 1; st < 256; st <<= 1) {
        int u = s[t];
        if (t >= st) u += s[t - st];
        __syncthreads();
        s[t] = u;
        __syncthreads();
    }
    cursorA[t * 256 + k] = s[t] - v;  // exclusive within column
    if (t == 255) tot[k] = s[255];
}

// exclusive scan of bucket totals -> bucketStart[0..256]
__global__ void kA_bscan(const int* __restrict__ tot, int* __restrict__ bucketStart) {
    __shared__ int s[256];
    int t = threadIdx.x;
    s[t] = tot[t];
    __syncthreads();
    for (int st = 1; st < 256; st <<= 1) {
        int u = s[t];
        if (t >= st) u += s[t - st];
        __syncthreads();
        s[t] = u;
        __syncthreads();
    }
    if (t == 0) bucketStart[0] = 0;
    bucketStart[t + 1] = s[t];
}

// scatter (src,dst) pairs into bucket-contiguous ebuf; each block writes its
// own contiguous slice of each bucket -> sequential writes per cursor
__global__ void kA_scatter(const int* __restrict__ src, const int* __restrict__ dst,
                           const int* __restrict__ cursorA,
                           const int* __restrict__ bucketStart,
                           int2* __restrict__ ebuf, int E, int chunk) {
    __shared__ int cur[256];
    int t = threadIdx.x;
    cur[t] = cursorA[blockIdx.x * 256 + t] + bucketStart[t];
    __syncthreads();
    int e0 = blockIdx.x * chunk;
    int e1 = min(e0 + chunk, E);
    for (int e = e0 + t; e < e1; e += 256) {
        int d = dst[e];
        int p = atomicAdd(&cur[d >> 8], 1);
        ebuf[p] = make_int2(src[e], d);
    }
}

// ---------------- pass B: per-bucket exact degree + final col scatter -------

// block per bucket: LDS histogram of dst&255 -> coalesced count & dis writes
__global__ void kB_count(const int2* __restrict__ ebuf, const int* __restrict__ bucketStart,
                         int* __restrict__ count, float* __restrict__ dis, int N) {
    __shared__ int h[256];
    int t = threadIdx.x;
    int k = blockIdx.x;
    h[t] = 0;
    __syncthreads();
    int lo = bucketStart[k], hi = bucketStart[k + 1];
    for (int p = lo + t; p < hi; p += 256) atomicAdd(&h[ebuf[p].y & 255], 1);
    __syncthreads();
    int node = k * 256 + t;
    if (node < N) {
        int c = h[t];
        count[node] = c;
        dis[node] = rsqrtf((float)(c + 1));  // +1 self-loop
    }
}

// block per bucket: scatter src into col within the bucket's contiguous window
__global__ void kB_scatter(const int2* __restrict__ ebuf, const int* __restrict__ bucketStart,
                           const int* __restrict__ offs, int* __restrict__ col, int N) {
    __shared__ int cur[256];
    int t = threadIdx.x;
    int k = blockIdx.x;
    int node = k * 256 + t;
    cur[t] = (node < N) ? offs[node] : 0;
    __syncthreads();
    int lo = bucketStart[k], hi = bucketStart[k + 1];
    for (int p = lo + t; p < hi; p += 256) {
        int2 e = ebuf[p];
        int q = atomicAdd(&cur[e.y & 255], 1);
        col[q] = e.x;
    }
}

// ---------------- offs scan over count (N elems, <=256*256) ----------------

__global__ void k_scan1(const int* __restrict__ count, int* __restrict__ bsum, int n) {
    __shared__ int s[256];
    int t = threadIdx.x;
    int i = blockIdx.x * 256 + t;
    s[t] = (i < n) ? count[i] : 0;
    __syncthreads();
    for (int st = 128; st > 0; st >>= 1) {
        if (t < st) s[t] += s[t + st];
        __syncthreads();
    }
    if (t == 0) bsum[blockIdx.x] = s[0];
}

__global__ void k_scan2(int* __restrict__ bsum, int nb) {
    __shared__ int s[256];
    int t = threadIdx.x;
    s[t] = (t < nb) ? bsum[t] : 0;
    __syncthreads();
    for (int st = 1; st < 256; st <<= 1) {
        int v = s[t];
        if (t >= st) v += s[t - st];
        __syncthreads();
        s[t] = v;
        __syncthreads();
    }
    if (t < nb) bsum[t] = (t == 0) ? 0 : s[t - 1];
}

__global__ void k_scan3(const int* __restrict__ count, const int* __restrict__ boffs,
                        int* __restrict__ offs, int n) {
    __shared__ int s[256];
    int t = threadIdx.x;
    int i = blockIdx.x * 256 + t;
    int c = (i < n) ? count[i] : 0;
    s[t] = c;
    __syncthreads();
    for (int st = 1; st < 256; st <<= 1) {
        int v = s[t];
        if (t >= st) v += s[t - st];
        __syncthreads();
        s[t] = v;
        __syncthreads();
    }
    int excl = s[t] - c;
    int off = boffs[blockIdx.x] + excl;
    if (i < n) {
        offs[i] = off;
        if (i == n - 1) offs[n] = off + c;
    }
}

// ---------------- dense transform + aggregate + pool/head -------------------

// H[n][0:64] = X[n][0:K] @ W[K][64]. 16 nodes/block, 16 lanes x float4 per node.
template <int K>
__global__ void k_gemm(const float* __restrict__ X, const float* __restrict__ W,
                       float* __restrict__ H, int n) {
    __shared__ float4 w4[K * 16];
    int t = threadIdx.x;
    const float4* W4 = (const float4*)W;
    for (int i = t; i < K * 16; i += 256) w4[i] = W4[i];
    __syncthreads();
    int node = blockIdx.x * 16 + (t >> 4);
    if (node >= n) return;
    int j4 = t & 15;
    const float4* X4 = (const float4*)(X + (size_t)node * K);
    float4 acc = make_float4(0.f, 0.f, 0.f, 0.f);
#pragma unroll 4
    for (int k0 = 0; k0 < K; k0 += 4) {
        float4 xv = X4[k0 >> 2];
        float4 a = w4[(k0 + 0) * 16 + j4];
        float4 b = w4[(k0 + 1) * 16 + j4];
        float4 c = w4[(k0 + 2) * 16 + j4];
        float4 d = w4[(k0 + 3) * 16 + j4];
        acc = f4fma(xv.x, a, acc);
        acc = f4fma(xv.y, b, acc);
        acc = f4fma(xv.z, c, acc);
        acc = f4fma(xv.w, d, acc);
    }
    ((float4*)H)[(size_t)node * 16 + j4] = acc;
}

// Out[n] = relu( dn*(H[n]*dn + sum_{s in in(n)} H[s]*dis[s]) + b ) [+ add1[n]+add2[n]]
__global__ void k_agg(const float* __restrict__ H, const int* __restrict__ col,
                      const int* __restrict__ offs, const float* __restrict__ dis,
                      const float* __restrict__ bias, const float* __restrict__ add1,
                      const float* __restrict__ add2, float* __restrict__ Out, int n) {
    int t = threadIdx.x;
    int node = blockIdx.x * 16 + (t >> 4);
    if (node >= n) return;
    int j4 = t & 15;
    const float4* H4 = (const float4*)H;
    float dn = dis[node];
    float4 acc = H4[(size_t)node * 16 + j4];
    acc.x *= dn; acc.y *= dn; acc.z *= dn; acc.w *= dn;
    int lo = offs[node], hi = offs[node + 1];
    int p = lo;
    for (; p + 2 <= hi; p += 2) {
        int s0 = col[p], s1 = col[p + 1];
        float w0 = dis[s0], w1 = dis[s1];
        float4 h0 = H4[(size_t)s0 * 16 + j4];
        float4 h1 = H4[(size_t)s1 * 16 + j4];
        acc = f4fma(w0, h0, acc);
        acc = f4fma(w1, h1, acc);
    }
    if (p < hi) {
        int s0 = col[p];
        acc = f4fma(dis[s0], H4[(size_t)s0 * 16 + j4], acc);
    }
    float4 b = ((const float4*)bias)[j4];
    float4 v;
    v.x = fmaxf(acc.x * dn + b.x, 0.f);
    v.y = fmaxf(acc.y * dn + b.y, 0.f);
    v.z = fmaxf(acc.z * dn + b.z, 0.f);
    v.w = fmaxf(acc.w * dn + b.w, 0.f);
    if (add1) {
        float4 a1 = ((const float4*)add1)[(size_t)node * 16 + j4];
        float4 a2 = ((const float4*)add2)[(size_t)node * 16 + j4];
        v.x += a1.x + a2.x; v.y += a1.y + a2.y; v.z += a1.z + a2.z; v.w += a1.w + a2.w;
    }
    ((float4*)Out)[(size_t)node * 16 + j4] = v;
}

// one 64-thread block per graph: segment mean (sorted batch, binary search) + MLP head
__global__ void k_poolhead(const float* __restrict__ S, const int* __restrict__ batch,
                           const float* __restrict__ Wp1, const float* __restrict__ bp1,
                           const float* __restrict__ Wp2, const float* __restrict__ bp2,
                           float* __restrict__ out, int n, int G) {
    int g = blockIdx.x;
    int j = threadIdx.x;  // 0..63
    int a = 0, b = n;
    while (a < b) { int m = (a + b) >> 1; if (batch[m] < g) a = m + 1; else b = m; }
    int beg = a;
    b = n;
    while (a < b) { int m = (a + b) >> 1; if (batch[m] < g + 1) a = m + 1; else b = m; }
    int end = a;
    float sum = 0.f;
    int i = beg;
    for (; i + 2 <= end; i += 2)
        sum += S[(size_t)i * 64 + j] + S[(size_t)(i + 1) * 64 + j];
    if (i < end) sum += S[(size_t)i * 64 + j];
    float cnt = (float)(end - beg);
    float p = sum / fmaxf(cnt, 1.f);
    __shared__ float ps[64];
    __shared__ float ts[64];
    ps[j] = p;
    __syncthreads();
    float t1 = bp1[j];
#pragma unroll 8
    for (int k = 0; k < 64; k++) t1 += ps[k] * Wp1[k * 64 + j];
    t1 = fmaxf(t1, 0.f);
    ts[j] = t1;
    __syncthreads();
    if (j < 32) {
        float o = bp2[j];
#pragma unroll 8
        for (int k = 0; k < 64; k++) o += ts[k] * Wp2[k * 32 + j];
        out[(size_t)g * 32 + j] = o;
    }
}

extern "C" void kernel_launch(void* const* d_in, const int* in_sizes, int n_in,
                              void* d_out, int out_size, void* d_ws, size_t ws_size,
                              hipStream_t stream) {
    const float* x   = (const float*)d_in[0];
    const int*   ei  = (const int*)d_in[1];
    const int*   bat = (const int*)d_in[2];
    const float* W1  = (const float*)d_in[3];
    const float* b1  = (const float*)d_in[4];
    const float* W2  = (const float*)d_in[5];
    const float* b2  = (const float*)d_in[6];
    const float* W3  = (const float*)d_in[7];
    const float* b3  = (const float*)d_in[8];
    const float* Wp1 = (const float*)d_in[9];
    const float* bp1 = (const float*)d_in[10];
    const float* Wp2 = (const float*)d_in[11];
    const float* bp2 = (const float*)d_in[12];

    int N = in_sizes[0] / 128;
    int E = in_sizes[1] / 2;
    int G = out_size / 32;
    const int* src = ei;
    const int* dst = ei + E;

    char* w = (char*)d_ws;
    auto alloc = [&](size_t bytes) -> void* {
        void* p = (void*)w;
        w += (bytes + 255) & ~(size_t)255;
        return p;
    };
    int NB  = (N + 255) / 256;   // node blocks (= coarse buckets), <= 256
    int BUK = NB;
    int*   count   = (int*)alloc((size_t)N * 4);
    int*   offs    = (int*)alloc((size_t)(N + 1) * 4);
    int*   col     = (int*)alloc((size_t)E * 4);
    int*   bsum    = (int*)alloc((size_t)NB * 4);
    float* dis     = (float*)alloc((size_t)N * 4);
    int*   hist    = (int*)alloc((size_t)256 * 256 * 4);
    int*   cursorA = (int*)alloc((size_t)256 * 256 * 4);
    int*   tot     = (int*)alloc((size_t)256 * 4);
    int*   bstart  = (int*)alloc((size_t)257 * 4);
    int2*  ebuf    = (int2*)alloc((size_t)E * 8);
    float* Hb      = (float*)alloc((size_t)N * 64 * 4);
    float* X1      = (float*)alloc((size_t)N * 64 * 4);
    float* X2      = (float*)alloc((size_t)N * 64 * 4);
    float* S       = (float*)alloc((size_t)N * 64 * 4);

    int chunk = (E + 255) / 256;  // edges per pass-A block

    kA_hist<<<256, 256, 0, stream>>>(dst, hist, E, chunk);
    kA_colscan<<<256, 256, 0, stream>>>(hist, cursorA, tot);
    kA_bscan<<<1, 256, 0, stream>>>(tot, bstart);
    kA_scatter<<<256, 256, 0, stream>>>(src, dst, cursorA, bstart, ebuf, E, chunk);
    kB_count<<<BUK, 256, 0, stream>>>(ebuf, bstart, count, dis, N);
    k_scan1<<<NB, 256, 0, stream>>>(count, bsum, N);
    k_scan2<<<1, 256, 0, stream>>>(bsum, NB);
    k_scan3<<<NB, 256, 0, stream>>>(count, bsum, offs, N);
    kB_scatter<<<BUK, 256, 0, stream>>>(ebuf, bstart, offs, col, N);

    int NB16 = (N + 15) / 16;
    k_gemm<128><<<NB16, 256, 0, stream>>>(x, W1, Hb, N);
    k_agg<<<NB16, 256, 0, stream>>>(Hb, col, offs, dis, b1, nullptr, nullptr, X1, N);
    k_gemm<64><<<NB16, 256, 0, stream>>>(X1, W2, Hb, N);
    k_agg<<<NB16, 256, 0, stream>>>(Hb, col, offs, dis, b2, nullptr, nullptr, X2, N);
    k_gemm<64><<<NB16, 256, 0, stream>>>(X2, W3, Hb, N);
    k_agg<<<NB16, 256, 0, stream>>>(Hb, col, offs, dis, b3, X1, X2, S, N);

    k_poolhead<<<G, 64, 0, stream>>>(S, bat, Wp1, bp1, Wp2, bp2, (float*)d_out, N, G);
}

// Round 4
// 282.083 us; speedup vs baseline: 2.0595x; 1.0313x over previous
//
#include <hip/hip_runtime.h>
#include <math.h>

// ---------------------------------------------------------------------------
// GNNEncoder: 3x GCNConv(relu) -> sum of layers -> global_mean_pool -> MLP
// CSR via two-level bucketed counting sort (all global writes block-contiguous).
// Pass B fused: degree+dis+offs+col in one kernel (offsets derive from
// bucketStart + local scan -- no global scan needed).
// GEMM: 4 nodes/thread register blocking (amortize LDS W reads).
// Agg: gather-based, 16 lanes x float4 per node, 4x edge unroll.
// ---------------------------------------------------------------------------

__device__ inline float4 f4fma(float s, float4 a, float4 acc) {
    acc.x += s * a.x; acc.y += s * a.y; acc.z += s * a.z; acc.w += s * a.w;
    return acc;
}
__device__ inline float f4c(const float4& v, int k) {
    return k == 0 ? v.x : k == 1 ? v.y : k == 2 ? v.z : v.w;
}

// ---------------- pass A: coarse bucket sort of edges by dst>>8 -------------

__global__ void kA_hist(const int* __restrict__ dst, int* __restrict__ hist,
                        int E, int chunk) {
    __shared__ int h[256];
    int t = threadIdx.x;
    h[t] = 0;
    __syncthreads();
    int e0 = blockIdx.x * chunk;
    int e1 = min(e0 + chunk, E);
    for (int e = e0 + t; e < e1; e += 256) atomicAdd(&h[dst[e] >> 8], 1);
    __syncthreads();
    hist[blockIdx.x * 256 + t] = h[t];
}

__global__ void kA_colscan(const int* __restrict__ hist, int* __restrict__ cursorA,
                           int* __restrict__ tot) {
    __shared__ int s[256];
    int t = threadIdx.x;
    int k = blockIdx.x;
    int v = hist[t * 256 + k];
    s[t] = v;
    __syncthreads();
    for (int st = 1; st < 256; st <<= 1) {
        int u = s[t];
        if (t >= st) u += s[t - st];
        __syncthreads();
        s[t] = u;
        __syncthreads();
    }
    cursorA[t * 256 + k] = s[t] - v;
    if (t == 255) tot[k] = s[255];
}

__global__ void kA_bscan(const int* __restrict__ tot, int* __restrict__ bucketStart) {
    __shared__ int s[256];
    int t = threadIdx.x;
    s[t] = tot[t];
    __syncthreads();
    for (int st = 1; st < 256; st <<= 1) {
        int u = s[t];
        if (t >= st) u += s[t - st];
        __syncthreads();
        s[t] = u;
        __syncthreads();
    }
    if (t == 0) bucketStart[0] = 0;
    bucketStart[t + 1] = s[t];
}

// scatter packed (dstLow<<24 | src) into bucket-contiguous ebuf
__global__ void kA_scatter(const int* __restrict__ src, const int* __restrict__ dst,
                           const int* __restrict__ cursorA,
                           const int* __restrict__ bucketStart,
                           unsigned* __restrict__ ebuf, int E, int chunk) {
    __shared__ int cur[256];
    int t = threadIdx.x;
    cur[t] = cursorA[blockIdx.x * 256 + t] + bucketStart[t];
    __syncthreads();
    int e0 = blockIdx.x * chunk;
    int e1 = min(e0 + chunk, E);
    for (int e = e0 + t; e < e1; e += 256) {
        int d = dst[e];
        int p = atomicAdd(&cur[d >> 8], 1);
        ebuf[p] = ((unsigned)(d & 255) << 24) | (unsigned)src[e];
    }
}

// ---------------- pass B (fused): degree + dis + offs + col scatter ---------

__global__ void kB(const unsigned* __restrict__ ebuf, const int* __restrict__ bucketStart,
                   float* __restrict__ dis, int* __restrict__ offs,
                   int* __restrict__ col, int N, int E) {
    __shared__ int h[256];
    __shared__ int s[256];
    __shared__ int cur[256];
    int t = threadIdx.x;
    int k = blockIdx.x;
    h[t] = 0;
    __syncthreads();
    int lo = bucketStart[k], hi = bucketStart[k + 1];
    for (int p = lo + t; p < hi; p += 256) atomicAdd(&h[ebuf[p] >> 24], 1);
    __syncthreads();
    int c = h[t];
    int node = k * 256 + t;
    if (node < N) dis[node] = rsqrtf((float)(c + 1));  // +1 self-loop
    // exclusive scan of h within the bucket
    s[t] = c;
    __syncthreads();
    for (int st = 1; st < 256; st <<= 1) {
        int v = s[t];
        if (t >= st) v += s[t - st];
        __syncthreads();
        s[t] = v;
        __syncthreads();
    }
    int start = lo + s[t] - c;
    cur[t] = start;
    if (node < N) offs[node] = start;
    if (node == N - 1) offs[N] = E;
    __syncthreads();
    for (int p = lo + t; p < hi; p += 256) {
        unsigned e = ebuf[p];
        int q = atomicAdd(&cur[e >> 24], 1);
        col[q] = (int)(e & 0xFFFFFFu >> 8 ? (e & 0x00FFFFFFu) : (e & 0x00FFFFFFu));
    }
}

// ---------------- dense transform: 64 nodes/block, 4 nodes/thread ----------

template <int K>
__global__ void k_gemm(const float* __restrict__ X, const float* __restrict__ W,
                       float* __restrict__ H, int n) {
    __shared__ float4 w4[K * 16];
    int t = threadIdx.x;
    const float4* W4 = (const float4*)W;
    for (int i = t; i < K * 16; i += 256) w4[i] = W4[i];
    __syncthreads();
    int j4 = t & 15;       // channel group (4 ch)
    int ng = t >> 4;       // node group
    int base = blockIdx.x * 64 + ng * 4;
    const float4* Xr[4];
#pragma unroll
    for (int m = 0; m < 4; m++) {
        int nm = min(base + m, n - 1);
        Xr[m] = (const float4*)(X + (size_t)nm * K);
    }
    float4 acc[4];
#pragma unroll
    for (int m = 0; m < 4; m++) acc[m] = make_float4(0.f, 0.f, 0.f, 0.f);
#pragma unroll 2
    for (int k0 = 0; k0 < K; k0 += 4) {
        float4 xv[4];
#pragma unroll
        for (int m = 0; m < 4; m++) xv[m] = Xr[m][k0 >> 2];
#pragma unroll
        for (int kk = 0; kk < 4; kk++) {
            float4 wv = w4[(k0 + kk) * 16 + j4];
#pragma unroll
            for (int m = 0; m < 4; m++) acc[m] = f4fma(f4c(xv[m], kk), wv, acc[m]);
        }
    }
#pragma unroll
    for (int m = 0; m < 4; m++)
        if (base + m < n)
            ((float4*)H)[(size_t)(base + m) * 16 + j4] = acc[m];
}

// Out[n] = relu( dn*(H[n]*dn + sum_{s in in(n)} H[s]*dis[s]) + b ) [+ add1+add2]
__global__ void k_agg(const float* __restrict__ H, const int* __restrict__ col,
                      const int* __restrict__ offs, const float* __restrict__ dis,
                      const float* __restrict__ bias, const float* __restrict__ add1,
                      const float* __restrict__ add2, float* __restrict__ Out, int n) {
    int t = threadIdx.x;
    int node = blockIdx.x * 16 + (t >> 4);
    if (node >= n) return;
    int j4 = t & 15;
    const float4* H4 = (const float4*)H;
    float dn = dis[node];
    float4 acc = H4[(size_t)node * 16 + j4];
    acc.x *= dn; acc.y *= dn; acc.z *= dn; acc.w *= dn;
    int lo = offs[node], hi = offs[node + 1];
    int p = lo;
    for (; p + 4 <= hi; p += 4) {
        int s0 = col[p], s1 = col[p + 1], s2 = col[p + 2], s3 = col[p + 3];
        float w0 = dis[s0], w1 = dis[s1], w2 = dis[s2], w3 = dis[s3];
        float4 h0 = H4[(size_t)s0 * 16 + j4];
        float4 h1 = H4[(size_t)s1 * 16 + j4];
        float4 h2 = H4[(size_t)s2 * 16 + j4];
        float4 h3 = H4[(size_t)s3 * 16 + j4];
        acc = f4fma(w0, h0, acc);
        acc = f4fma(w1, h1, acc);
        acc = f4fma(w2, h2, acc);
        acc = f4fma(w3, h3, acc);
    }
    for (; p < hi; p++) {
        int s0 = col[p];
        acc = f4fma(dis[s0], H4[(size_t)s0 * 16 + j4], acc);
    }
    float4 b = ((const float4*)bias)[j4];
    float4 v;
    v.x = fmaxf(acc.x * dn + b.x, 0.f);
    v.y = fmaxf(acc.y * dn + b.y, 0.f);
    v.z = fmaxf(acc.z * dn + b.z, 0.f);
    v.w = fmaxf(acc.w * dn + b.w, 0.f);
    if (add1) {
        float4 a1 = ((const float4*)add1)[(size_t)node * 16 + j4];
        float4 a2 = ((const float4*)add2)[(size_t)node * 16 + j4];
        v.x += a1.x + a2.x; v.y += a1.y + a2.y; v.z += a1.z + a2.z; v.w += a1.w + a2.w;
    }
    ((float4*)Out)[(size_t)node * 16 + j4] = v;
}

// one 64-thread block per graph: segment mean (sorted batch) + MLP head
__global__ void k_poolhead(const float* __restrict__ S, const int* __restrict__ batch,
                           const float* __restrict__ Wp1, const float* __restrict__ bp1,
                           const float* __restrict__ Wp2, const float* __restrict__ bp2,
                           float* __restrict__ out, int n, int G) {
    int g = blockIdx.x;
    int j = threadIdx.x;  // 0..63
    int a = 0, b = n;
    while (a < b) { int m = (a + b) >> 1; if (batch[m] < g) a = m + 1; else b = m; }
    int beg = a;
    b = n;
    while (a < b) { int m = (a + b) >> 1; if (batch[m] < g + 1) a = m + 1; else b = m; }
    int end = a;
    float sum = 0.f;
    int i = beg;
    for (; i + 2 <= end; i += 2)
        sum += S[(size_t)i * 64 + j] + S[(size_t)(i + 1) * 64 + j];
    if (i < end) sum += S[(size_t)i * 64 + j];
    float cnt = (float)(end - beg);
    float p = sum / fmaxf(cnt, 1.f);
    __shared__ float ps[64];
    __shared__ float ts[64];
    ps[j] = p;
    __syncthreads();
    float t1 = bp1[j];
#pragma unroll 8
    for (int k = 0; k < 64; k++) t1 += ps[k] * Wp1[k * 64 + j];
    t1 = fmaxf(t1, 0.f);
    ts[j] = t1;
    __syncthreads();
    if (j < 32) {
        float o = bp2[j];
#pragma unroll 8
        for (int k = 0; k < 64; k++) o += ts[k] * Wp2[k * 32 + j];
        out[(size_t)g * 32 + j] = o;
    }
}

extern "C" void kernel_launch(void* const* d_in, const int* in_sizes, int n_in,
                              void* d_out, int out_size, void* d_ws, size_t ws_size,
                              hipStream_t stream) {
    const float* x   = (const float*)d_in[0];
    const int*   ei  = (const int*)d_in[1];
    const int*   bat = (const int*)d_in[2];
    const float* W1  = (const float*)d_in[3];
    const float* b1  = (const float*)d_in[4];
    const float* W2  = (const float*)d_in[5];
    const float* b2  = (const float*)d_in[6];
    const float* W3  = (const float*)d_in[7];
    const float* b3  = (const float*)d_in[8];
    const float* Wp1 = (const float*)d_in[9];
    const float* bp1 = (const float*)d_in[10];
    const float* Wp2 = (const float*)d_in[11];
    const float* bp2 = (const float*)d_in[12];

    int N = in_sizes[0] / 128;
    int E = in_sizes[1] / 2;
    int G = out_size / 32;
    const int* src = ei;
    const int* dst = ei + E;

    char* w = (char*)d_ws;
    auto alloc = [&](size_t bytes) -> void* {
        void* p = (void*)w;
        w += (bytes + 255) & ~(size_t)255;
        return p;
    };
    int NB = (N + 255) / 256;  // buckets (<=256)
    int*      offs    = (int*)alloc((size_t)(N + 1) * 4);
    int*      col     = (int*)alloc((size_t)E * 4);
    float*    dis     = (float*)alloc((size_t)N * 4);
    int*      hist    = (int*)alloc((size_t)256 * 256 * 4);
    int*      cursorA = (int*)alloc((size_t)256 * 256 * 4);
    int*      tot     = (int*)alloc((size_t)256 * 4);
    int*      bstart  = (int*)alloc((size_t)257 * 4);
    unsigned* ebuf    = (unsigned*)alloc((size_t)E * 4);
    float*    Hb      = (float*)alloc((size_t)N * 64 * 4);
    float*    X1      = (float*)alloc((size_t)N * 64 * 4);
    float*    X2      = (float*)alloc((size_t)N * 64 * 4);
    float*    S       = (float*)alloc((size_t)N * 64 * 4);

    int chunk = (E + 255) / 256;

    kA_hist<<<256, 256, 0, stream>>>(dst, hist, E, chunk);
    kA_colscan<<<256, 256, 0, stream>>>(hist, cursorA, tot);
    kA_bscan<<<1, 256, 0, stream>>>(tot, bstart);
    kA_scatter<<<256, 256, 0, stream>>>(src, dst, cursorA, bstart, ebuf, E, chunk);
    kB<<<NB, 256, 0, stream>>>(ebuf, bstart, dis, offs, col, N, E);

    int NB64 = (N + 63) / 64;
    int NB16 = (N + 15) / 16;
    k_gemm<128><<<NB64, 256, 0, stream>>>(x, W1, Hb, N);
    k_agg<<<NB16, 256, 0, stream>>>(Hb, col, offs, dis, b1, nullptr, nullptr, X1, N);
    k_gemm<64><<<NB64, 256, 0, stream>>>(X1, W2, Hb, N);
    k_agg<<<NB16, 256, 0, stream>>>(Hb, col, offs, dis, b2, nullptr, nullptr, X2, N);
    k_gemm<64><<<NB64, 256, 0, stream>>>(X2, W3, Hb, N);
    k_agg<<<NB16, 256, 0, stream>>>(Hb, col, offs, dis, b3, X1, X2, S, N);

    k_poolhead<<<G, 64, 0, stream>>>(S, bat, Wp1, bp1, Wp2, bp2, (float*)d_out, N, G);
}

// Round 5
// 281.970 us; speedup vs baseline: 2.0603x; 1.0004x over previous
//
#include <hip/hip_runtime.h>
#include <math.h>

// ---------------------------------------------------------------------------
// GNNEncoder: 3x GCNConv(relu) -> sum of layers -> global_mean_pool -> MLP
// CSR via bucketed counting sort (block-contiguous writes). H stored bf16 to
// halve gather traffic; col2 carries (src, dis[src]) so aggs do zero random
// dis lookups. Aggregation: gather-based, 16 lanes x 4ch per node, 4x unroll.
// ---------------------------------------------------------------------------

__device__ inline float bf2f(unsigned short h) {
    return __uint_as_float((unsigned)h << 16);
}
__device__ inline float4 bh4f(ushort4 u) {
    return make_float4(bf2f(u.x), bf2f(u.y), bf2f(u.z), bf2f(u.w));
}
__device__ inline unsigned short f2bf(float f) {  // round-to-nearest-even
    unsigned u = __float_as_uint(f);
    return (unsigned short)((u + (0x7FFFu + ((u >> 16) & 1u))) >> 16);
}
__device__ inline float4 f4fma(float s, float4 a, float4 acc) {
    acc.x += s * a.x; acc.y += s * a.y; acc.z += s * a.z; acc.w += s * a.w;
    return acc;
}
__device__ inline float f4c(const float4& v, int k) {
    return k == 0 ? v.x : k == 1 ? v.y : k == 2 ? v.z : v.w;
}

// ---- pass A: coarse bucket hist (dst>>8) + per-node degree (global atomics)
__global__ void kA_hist(const int* __restrict__ dst, int* __restrict__ hist,
                        int* __restrict__ count, int E, int chunk) {
    __shared__ int h[256];
    int t = threadIdx.x;
    h[t] = 0;
    __syncthreads();
    int e0 = blockIdx.x * chunk;
    int e1 = min(e0 + chunk, E);
    for (int e = e0 + t; e < e1; e += 256) {
        int d = dst[e];
        atomicAdd(&h[d >> 8], 1);
        atomicAdd(&count[d], 1);
    }
    __syncthreads();
    hist[blockIdx.x * 256 + t] = h[t];
}

// block k scans column k of hist over chunk-blocks -> cursorA, tot; also dis
__global__ void kA_colscan(const int* __restrict__ hist, int* __restrict__ cursorA,
                           int* __restrict__ tot, const int* __restrict__ count,
                           float* __restrict__ dis, int N) {
    __shared__ int s[256];
    int t = threadIdx.x;
    int k = blockIdx.x;
    int v = hist[t * 256 + k];
    s[t] = v;
    __syncthreads();
    for (int st = 1; st < 256; st <<= 1) {
        int u = s[t];
        if (t >= st) u += s[t - st];
        __syncthreads();
        s[t] = u;
        __syncthreads();
    }
    cursorA[t * 256 + k] = s[t] - v;
    if (t == 255) tot[k] = s[255];
    int i = k * 256 + t;  // 65536 slots cover N
    if (i < N) dis[i] = rsqrtf((float)(count[i] + 1));  // +1 self-loop
}

// scatter packed (dstLow<<24 | src) into bucket-contiguous ebuf (bstart inline)
__global__ void kA_scatter(const int* __restrict__ src, const int* __restrict__ dst,
                           const int* __restrict__ cursorA, const int* __restrict__ tot,
                           unsigned* __restrict__ ebuf, int E, int chunk) {
    __shared__ int s[256];
    __shared__ int cur[256];
    int t = threadIdx.x;
    s[t] = tot[t];
    __syncthreads();
    for (int st = 1; st < 256; st <<= 1) {
        int u = s[t];
        if (t >= st) u += s[t - st];
        __syncthreads();
        s[t] = u;
        __syncthreads();
    }
    int bstart = (t == 0) ? 0 : s[t - 1];
    cur[t] = cursorA[blockIdx.x * 256 + t] + bstart;
    __syncthreads();
    int e0 = blockIdx.x * chunk;
    int e1 = min(e0 + chunk, E);
    for (int e = e0 + t; e < e1; e += 256) {
        int d = dst[e];
        int p = atomicAdd(&cur[d >> 8], 1);
        ebuf[p] = ((unsigned)(d & 255) << 24) | (unsigned)src[e];
    }
}

// pass B fused: per-bucket degree hist -> offs; scatter col2 = (src, dis[src])
__global__ void kB(const unsigned* __restrict__ ebuf, const int* __restrict__ tot,
                   const float* __restrict__ dis, int* __restrict__ offs,
                   float2* __restrict__ col2, int N, int E) {
    __shared__ int s[256];
    __shared__ int h[256];
    __shared__ int cur[256];
    int t = threadIdx.x;
    int k = blockIdx.x;
    s[t] = tot[t];
    __syncthreads();
    for (int st = 1; st < 256; st <<= 1) {
        int u = s[t];
        if (t >= st) u += s[t - st];
        __syncthreads();
        s[t] = u;
        __syncthreads();
    }
    int lo = (k == 0) ? 0 : s[k - 1];
    int hi = s[k];
    h[t] = 0;
    __syncthreads();
    for (int p = lo + t; p < hi; p += 256) atomicAdd(&h[ebuf[p] >> 24], 1);
    __syncthreads();
    int c = h[t];
    s[t] = c;
    __syncthreads();
    for (int st = 1; st < 256; st <<= 1) {
        int u = s[t];
        if (t >= st) u += s[t - st];
        __syncthreads();
        s[t] = u;
        __syncthreads();
    }
    int start = lo + s[t] - c;
    cur[t] = start;
    int node = k * 256 + t;
    if (node < N) offs[node] = start;
    if (node == N - 1) offs[N] = E;
    __syncthreads();
    for (int p = lo + t; p < hi; p += 256) {
        unsigned e = ebuf[p];
        int srcI = (int)(e & 0x00FFFFFFu);
        int q = atomicAdd(&cur[e >> 24], 1);
        col2[q] = make_float2(__int_as_float(srcI), dis[srcI]);
    }
}

// ---- dense transform: 64 nodes/block, 4 nodes/thread; bf16 output ----------
template <int K>
__global__ void k_gemm(const float* __restrict__ X, const float* __restrict__ W,
                       unsigned short* __restrict__ H, int n) {
    __shared__ float4 w4[K * 16];
    int t = threadIdx.x;
    const float4* W4 = (const float4*)W;
    for (int i = t; i < K * 16; i += 256) w4[i] = W4[i];
    __syncthreads();
    int j4 = t & 15;
    int ng = t >> 4;
    int base = blockIdx.x * 64 + ng * 4;
    const float4* Xr[4];
#pragma unroll
    for (int m = 0; m < 4; m++) {
        int nm = min(base + m, n - 1);
        Xr[m] = (const float4*)(X + (size_t)nm * K);
    }
    float4 acc[4];
#pragma unroll
    for (int m = 0; m < 4; m++) acc[m] = make_float4(0.f, 0.f, 0.f, 0.f);
#pragma unroll 2
    for (int k0 = 0; k0 < K; k0 += 4) {
        float4 xv[4];
#pragma unroll
        for (int m = 0; m < 4; m++) xv[m] = Xr[m][k0 >> 2];
#pragma unroll
        for (int kk = 0; kk < 4; kk++) {
            float4 wv = w4[(k0 + kk) * 16 + j4];
#pragma unroll
            for (int m = 0; m < 4; m++) acc[m] = f4fma(f4c(xv[m], kk), wv, acc[m]);
        }
    }
#pragma unroll
    for (int m = 0; m < 4; m++)
        if (base + m < n) {
            ushort4 u;
            u.x = f2bf(acc[m].x); u.y = f2bf(acc[m].y);
            u.z = f2bf(acc[m].z); u.w = f2bf(acc[m].w);
            ((ushort4*)H)[(size_t)(base + m) * 16 + j4] = u;
        }
}

// Out[n] = relu( dn*(H[n]*dn + sum_{(s,w) in in(n)} H[s]*w) + b ) [+ add1+add2]
__global__ void k_agg(const unsigned short* __restrict__ H, const float2* __restrict__ col2,
                      const int* __restrict__ offs, const float* __restrict__ dis,
                      const float* __restrict__ bias, const float* __restrict__ add1,
                      const float* __restrict__ add2, float* __restrict__ Out, int n) {
    int t = threadIdx.x;
    int node = blockIdx.x * 16 + (t >> 4);
    if (node >= n) return;
    int j4 = t & 15;
    const ushort4* H4 = (const ushort4*)H;
    float dn = dis[node];
    float4 acc = bh4f(H4[(size_t)node * 16 + j4]);
    acc.x *= dn; acc.y *= dn; acc.z *= dn; acc.w *= dn;
    int lo = offs[node], hi = offs[node + 1];
    int p = lo;
    for (; p + 4 <= hi; p += 4) {
        float2 e0 = col2[p], e1 = col2[p + 1], e2 = col2[p + 2], e3 = col2[p + 3];
        int s0 = __float_as_int(e0.x), s1 = __float_as_int(e1.x);
        int s2 = __float_as_int(e2.x), s3 = __float_as_int(e3.x);
        float4 h0 = bh4f(H4[(size_t)s0 * 16 + j4]);
        float4 h1 = bh4f(H4[(size_t)s1 * 16 + j4]);
        float4 h2 = bh4f(H4[(size_t)s2 * 16 + j4]);
        float4 h3 = bh4f(H4[(size_t)s3 * 16 + j4]);
        acc = f4fma(e0.y, h0, acc);
        acc = f4fma(e1.y, h1, acc);
        acc = f4fma(e2.y, h2, acc);
        acc = f4fma(e3.y, h3, acc);
    }
    for (; p < hi; p++) {
        float2 e = col2[p];
        acc = f4fma(e.y, bh4f(H4[(size_t)__float_as_int(e.x) * 16 + j4]), acc);
    }
    float4 b = ((const float4*)bias)[j4];
    float4 v;
    v.x = fmaxf(acc.x * dn + b.x, 0.f);
    v.y = fmaxf(acc.y * dn + b.y, 0.f);
    v.z = fmaxf(acc.z * dn + b.z, 0.f);
    v.w = fmaxf(acc.w * dn + b.w, 0.f);
    if (add1) {
        float4 a1 = ((const float4*)add1)[(size_t)node * 16 + j4];
        float4 a2 = ((const float4*)add2)[(size_t)node * 16 + j4];
        v.x += a1.x + a2.x; v.y += a1.y + a2.y; v.z += a1.z + a2.z; v.w += a1.w + a2.w;
    }
    ((float4*)Out)[(size_t)node * 16 + j4] = v;
}

// one 64-thread block per graph: segment mean (sorted batch) + MLP head
__global__ void k_poolhead(const float* __restrict__ S, const int* __restrict__ batch,
                           const float* __restrict__ Wp1, const float* __restrict__ bp1,
                           const float* __restrict__ Wp2, const float* __restrict__ bp2,
                           float* __restrict__ out, int n, int G) {
    int g = blockIdx.x;
    int j = threadIdx.x;  // 0..63
    int a = 0, b = n;
    while (a < b) { int m = (a + b) >> 1; if (batch[m] < g) a = m + 1; else b = m; }
    int beg = a;
    b = n;
    while (a < b) { int m = (a + b) >> 1; if (batch[m] < g + 1) a = m + 1; else b = m; }
    int end = a;
    float sum = 0.f;
    int i = beg;
    for (; i + 2 <= end; i += 2)
        sum += S[(size_t)i * 64 + j] + S[(size_t)(i + 1) * 64 + j];
    if (i < end) sum += S[(size_t)i * 64 + j];
    float cnt = (float)(end - beg);
    float p = sum / fmaxf(cnt, 1.f);
    __shared__ float ps[64];
    __shared__ float ts[64];
    ps[j] = p;
    __syncthreads();
    float t1 = bp1[j];
#pragma unroll 8
    for (int k = 0; k < 64; k++) t1 += ps[k] * Wp1[k * 64 + j];
    t1 = fmaxf(t1, 0.f);
    ts[j] = t1;
    __syncthreads();
    if (j < 32) {
        float o = bp2[j];
#pragma unroll 8
        for (int k = 0; k < 64; k++) o += ts[k] * Wp2[k * 32 + j];
        out[(size_t)g * 32 + j] = o;
    }
}

extern "C" void kernel_launch(void* const* d_in, const int* in_sizes, int n_in,
                              void* d_out, int out_size, void* d_ws, size_t ws_size,
                              hipStream_t stream) {
    const float* x   = (const float*)d_in[0];
    const int*   ei  = (const int*)d_in[1];
    const int*   bat = (const int*)d_in[2];
    const float* W1  = (const float*)d_in[3];
    const float* b1  = (const float*)d_in[4];
    const float* W2  = (const float*)d_in[5];
    const float* b2  = (const float*)d_in[6];
    const float* W3  = (const float*)d_in[7];
    const float* b3  = (const float*)d_in[8];
    const float* Wp1 = (const float*)d_in[9];
    const float* bp1 = (const float*)d_in[10];
    const float* Wp2 = (const float*)d_in[11];
    const float* bp2 = (const float*)d_in[12];

    int N = in_sizes[0] / 128;
    int E = in_sizes[1] / 2;
    int G = out_size / 32;
    const int* src = ei;
    const int* dst = ei + E;

    char* w = (char*)d_ws;
    auto alloc = [&](size_t bytes) -> void* {
        void* p = (void*)w;
        w += (bytes + 255) & ~(size_t)255;
        return p;
    };
    int NB = (N + 255) / 256;  // buckets (<=256)
    int*            count   = (int*)alloc((size_t)N * 4);
    int*            offs    = (int*)alloc((size_t)(N + 1) * 4);
    float2*         col2    = (float2*)alloc((size_t)E * 8);
    float*          dis     = (float*)alloc((size_t)N * 4);
    int*            hist    = (int*)alloc((size_t)256 * 256 * 4);
    int*            cursorA = (int*)alloc((size_t)256 * 256 * 4);
    int*            tot     = (int*)alloc((size_t)256 * 4);
    unsigned*       ebuf    = (unsigned*)alloc((size_t)E * 4);
    unsigned short* Hb      = (unsigned short*)alloc((size_t)N * 64 * 2);
    float*          X1      = (float*)alloc((size_t)N * 64 * 4);
    float*          X2      = (float*)alloc((size_t)N * 64 * 4);
    float*          S       = (float*)alloc((size_t)N * 64 * 4);

    int chunk = (E + 255) / 256;

    hipMemsetAsync(count, 0, (size_t)N * 4, stream);
    kA_hist<<<256, 256, 0, stream>>>(dst, hist, count, E, chunk);
    kA_colscan<<<256, 256, 0, stream>>>(hist, cursorA, tot, count, dis, N);
    kA_scatter<<<256, 256, 0, stream>>>(src, dst, cursorA, tot, ebuf, E, chunk);
    kB<<<NB, 256, 0, stream>>>(ebuf, tot, dis, offs, col2, N, E);

    int NB64 = (N + 63) / 64;
    int NB16 = (N + 15) / 16;
    k_gemm<128><<<NB64, 256, 0, stream>>>(x, W1, Hb, N);
    k_agg<<<NB16, 256, 0, stream>>>(Hb, col2, offs, dis, b1, nullptr, nullptr, X1, N);
    k_gemm<64><<<NB64, 256, 0, stream>>>(X1, W2, Hb, N);
    k_agg<<<NB16, 256, 0, stream>>>(Hb, col2, offs, dis, b2, nullptr, nullptr, X2, N);
    k_gemm<64><<<NB64, 256, 0, stream>>>(X2, W3, Hb, N);
    k_agg<<<NB16, 256, 0, stream>>>(Hb, col2, offs, dis, b3, X1, X2, S, N);

    k_poolhead<<<G, 64, 0, stream>>>(S, bat, Wp1, bp1, Wp2, bp2, (float*)d_out, N, G);
}